// Round 2
// baseline (510.981 us; speedup 1.0000x reference)
//
#include <hip/hip_runtime.h>
#include <stdint.h>

// GraphiT GT layer, B=4, N=512, D=64, H=8, DH=8.
// K1: x = LN(h+p); Q1,K1s,V,Q2,K2s projections (K's pre-scaled by 8^-0.5)
// K2: per (b,i): scores/softmax-free streaming attention using MFMA for e@W_E|W_E2
// K3: h2 = h + hatt@O_W + O_b; out = h2 + FFN(LN2(h2))

typedef __attribute__((ext_vector_type(8))) short short8;
typedef __attribute__((ext_vector_type(4))) float f32x4;

__device__ __forceinline__ unsigned short f2bf(float f) {
    unsigned int u = __float_as_uint(f);
    u = (u + 0x7fffu + ((u >> 16) & 1u)) >> 16;   // RNE to bf16
    return (unsigned short)u;
}

__device__ __forceinline__ float wredsum(float v) {
    v += __shfl_xor(v, 1, 64);
    v += __shfl_xor(v, 2, 64);
    v += __shfl_xor(v, 4, 64);
    v += __shfl_xor(v, 8, 64);
    v += __shfl_xor(v, 16, 64);
    v += __shfl_xor(v, 32, 64);
    return v;
}

// ---------------- K1: LN(h+p) + 5 projections ----------------
__global__ __launch_bounds__(256) void k1_ln_proj(
    const float* __restrict__ h, const float* __restrict__ p,
    const float* __restrict__ WQ, const float* __restrict__ WK,
    const float* __restrict__ WV, const float* __restrict__ WQ2,
    const float* __restrict__ WK2,
    const float* __restrict__ g1, const float* __restrict__ b1,
    float* __restrict__ Q1w, float* __restrict__ K1w,
    float* __restrict__ Vw, float* __restrict__ Q2w, float* __restrict__ K2w)
{
    __shared__ float xl[16][64];
    int tid = threadIdx.x, lane = tid & 63, w = tid >> 6;
    int row0 = blockIdx.x * 16;
    for (int rr = 0; rr < 4; ++rr) {
        int r = w * 4 + rr;
        int row = row0 + r;
        float v = h[row * 64 + lane] + p[row * 64 + lane];
        float m = wredsum(v) * (1.0f / 64.0f);
        float t = v - m;
        float var = wredsum(t * t) * (1.0f / 64.0f);
        xl[r][lane] = t * rsqrtf(var + 1e-5f) * g1[lane] + b1[lane];
    }
    __syncthreads();
    const float* Ws[5] = {WQ, WK, WV, WQ2, WK2};
    float* Os[5] = {Q1w, K1w, Vw, Q2w, K2w};
    const float scale = 0.35355339059327373f; // DH^-0.5
    for (int idx = tid; idx < 5 * 16 * 64; idx += 256) {
        int m = idx >> 10;
        int rem = idx & 1023;
        int r = rem >> 6;
        int c = rem & 63;
        const float* W = Ws[m];
        float acc = 0.f;
        #pragma unroll 8
        for (int d = 0; d < 64; ++d) acc += xl[r][d] * W[d * 64 + c];
        if (m == 1 || m == 4) acc *= scale;
        Os[m][(row0 + r) * 64 + c] = acc;
    }
}

// ---------------- K2: main fused attention ----------------
// block = (b,i); 256 threads = 4 waves; each wave handles 8 tiles of 16 j's.
__global__ __launch_bounds__(256) void k2_attn(
    const float* __restrict__ e, const int* __restrict__ adj,
    const float* __restrict__ kRW, const float* __restrict__ mask,
    const float* __restrict__ WE, const float* __restrict__ WE2,
    const float* __restrict__ Q1w, const float* __restrict__ K1w,
    const float* __restrict__ Q2w, const float* __restrict__ K2w,
    const float* __restrict__ Vw, float* __restrict__ hatt)
{
    __shared__ __align__(16) float EvL[4][16][132];  // per-wave Ev tiles (cols 0..63 = E*Q1, 64..127 = E2*Q2)
    __shared__ float red[4][4][18];
    int tid = threadIdx.x, lane = tid & 63, w = tid >> 6;
    int lm = lane & 15, lg = lane >> 4;
    int blk = blockIdx.x;
    int b = blk >> 9, i = blk & 511;
    const float mi = mask[b * 512 + i];

    // B fragments: W_E (and W_E2) columns scaled by Q1 (Q2) of this row i.
    // mfma 16x16x32 bf16 B layout: lane holds B[k = 8*(lane/16)+e][col = lane%16]
    short8 bf[2][4][2];
    {
        const float* Q1r = Q1w + (size_t)blk * 64;
        const float* Q2r = Q2w + (size_t)blk * 64;
        #pragma unroll
        for (int mat = 0; mat < 2; ++mat) {
            const float* W = mat ? WE2 : WE;
            const float* Qr = mat ? Q2r : Q1r;
            #pragma unroll
            for (int t = 0; t < 4; ++t) {
                int c = t * 16 + lm;
                float qv = Qr[c];
                #pragma unroll
                for (int s = 0; s < 2; ++s) {
                    short8 v;
                    #pragma unroll
                    for (int ei = 0; ei < 8; ++ei)
                        v[ei] = (short)f2bf(W[(s * 32 + lg * 8 + ei) * 64 + c] * qv);
                    bf[mat][t][s] = v;
                }
            }
        }
    }

    float nr[16];
    #pragma unroll
    for (int q = 0; q < 16; ++q) nr[q] = 0.f;
    float den0 = 0.f, den1 = 0.f;

    const float* eblk = e + (size_t)blk * 32768;
    int jl = lane >> 2, pp = lane & 3;

    for (int it = 0; it < 8; ++it) {
        int jbase = (it * 4 + w) * 16;
        // A fragments: lane holds e_tile[row = lane%16][k = 8*(lane/16)+e] per 32-wide K step
        const float* erow = eblk + (size_t)(jbase + lm) * 64 + lg * 8;
        float4 f0 = *(const float4*)(erow);
        float4 f1 = *(const float4*)(erow + 4);
        float4 f2v = *(const float4*)(erow + 32);
        float4 f3 = *(const float4*)(erow + 36);
        short8 a0, a1;
        a0[0]=(short)f2bf(f0.x); a0[1]=(short)f2bf(f0.y); a0[2]=(short)f2bf(f0.z); a0[3]=(short)f2bf(f0.w);
        a0[4]=(short)f2bf(f1.x); a0[5]=(short)f2bf(f1.y); a0[6]=(short)f2bf(f1.z); a0[7]=(short)f2bf(f1.w);
        a1[0]=(short)f2bf(f2v.x); a1[1]=(short)f2bf(f2v.y); a1[2]=(short)f2bf(f2v.z); a1[3]=(short)f2bf(f2v.w);
        a1[4]=(short)f2bf(f3.x); a1[5]=(short)f2bf(f3.y); a1[6]=(short)f2bf(f3.z); a1[7]=(short)f2bf(f3.w);

        #pragma unroll
        for (int mat = 0; mat < 2; ++mat) {
            #pragma unroll
            for (int t = 0; t < 4; ++t) {
                f32x4 acc = {0.f, 0.f, 0.f, 0.f};
                acc = __builtin_amdgcn_mfma_f32_16x16x32_bf16(a0, bf[mat][t][0], acc, 0, 0, 0);
                acc = __builtin_amdgcn_mfma_f32_16x16x32_bf16(a1, bf[mat][t][1], acc, 0, 0, 0);
                // C/D layout (m89-verified): col = lane&15, row = (lane>>4)*4 + reg
                #pragma unroll
                for (int ei = 0; ei < 4; ++ei)
                    EvL[w][lg * 4 + ei][mat * 64 + t * 16 + lm] = acc[ei];
            }
        }
        __syncthreads();

        // phase 2: 4 lanes per j; lane pp owns flat hk in [pp*16, pp*16+16) == heads 2pp, 2pp+1
        int j = jbase + jl;
        size_t pair = (size_t)blk * 512 + j;
        int av = adj[pair];
        float kk = kRW[pair];
        float mj = mask[b * 512 + j];
        size_t jrow = (size_t)(b * 512 + j) * 64 + pp * 16;
        const float* Ks = (av ? K1w : K2w) + jrow;
        const float* Vp = Vw + jrow;
        const float* Evp = &EvL[w][jl][(av ? 0 : 64) + pp * 16];

        float4 ev0 = *(const float4*)(Evp);
        float4 ev1 = *(const float4*)(Evp + 4);
        float4 ev2 = *(const float4*)(Evp + 8);
        float4 ev3 = *(const float4*)(Evp + 12);
        float4 ka = *(const float4*)(Ks);
        float4 kb = *(const float4*)(Ks + 4);
        float4 kc = *(const float4*)(Ks + 8);
        float4 kd = *(const float4*)(Ks + 12);
        float s0 = ev0.x*ka.x + ev0.y*ka.y + ev0.z*ka.z + ev0.w*ka.w
                 + ev1.x*kb.x + ev1.y*kb.y + ev1.z*kb.z + ev1.w*kb.w;
        float s1 = ev2.x*kc.x + ev2.y*kc.y + ev2.z*kc.z + ev2.w*kc.w
                 + ev3.x*kd.x + ev3.y*kd.y + ev3.z*kd.z + ev3.w*kd.w;
        float w0 = __expf(s0) * kk * mj * mi;
        float w1 = __expf(s1) * kk * mj * mi;

        float4 va = *(const float4*)(Vp);
        float4 vb = *(const float4*)(Vp + 4);
        float4 vc = *(const float4*)(Vp + 8);
        float4 vd = *(const float4*)(Vp + 12);
        nr[0] += w0 * va.x;  nr[1] += w0 * va.y;  nr[2] += w0 * va.z;  nr[3] += w0 * va.w;
        nr[4] += w0 * vb.x;  nr[5] += w0 * vb.y;  nr[6] += w0 * vb.z;  nr[7] += w0 * vb.w;
        nr[8] += w1 * vc.x;  nr[9] += w1 * vc.y;  nr[10] += w1 * vc.z; nr[11] += w1 * vc.w;
        nr[12] += w1 * vd.x; nr[13] += w1 * vd.y; nr[14] += w1 * vd.z; nr[15] += w1 * vd.w;
        den0 += w0; den1 += w1;
        __syncthreads();
    }

    // reduce across the 16 j-owner lanes per pp within the wave
    #pragma unroll
    for (int q = 0; q < 16; ++q) {
        nr[q] += __shfl_xor(nr[q], 4, 64);
        nr[q] += __shfl_xor(nr[q], 8, 64);
        nr[q] += __shfl_xor(nr[q], 16, 64);
        nr[q] += __shfl_xor(nr[q], 32, 64);
    }
    den0 += __shfl_xor(den0, 4, 64); den0 += __shfl_xor(den0, 8, 64);
    den0 += __shfl_xor(den0, 16, 64); den0 += __shfl_xor(den0, 32, 64);
    den1 += __shfl_xor(den1, 4, 64); den1 += __shfl_xor(den1, 8, 64);
    den1 += __shfl_xor(den1, 16, 64); den1 += __shfl_xor(den1, 32, 64);

    if (jl == 0) {  // lanes 0..3 carry pp = 0..3
        #pragma unroll
        for (int q = 0; q < 16; ++q) red[w][pp][q] = nr[q];
        red[w][pp][16] = den0;
        red[w][pp][17] = den1;
    }
    __syncthreads();
    if (tid < 64) {
        int p2 = tid >> 4, q = tid & 15;
        float ns = red[0][p2][q] + red[1][p2][q] + red[2][p2][q] + red[3][p2][q];
        int di = 16 + (q >> 3);
        float ds = red[0][p2][di] + red[1][p2][di] + red[2][p2][di] + red[3][p2][di];
        hatt[(size_t)blk * 64 + p2 * 16 + q] = ns / fmaxf(ds, 1e-6f);
    }
}

// ---------------- K3: output projection + residual + LN2 + FFN ----------------
__global__ __launch_bounds__(256) void k3_out(
    const float* __restrict__ hatt, const float* __restrict__ h,
    const float* __restrict__ OW, const float* __restrict__ Ob,
    const float* __restrict__ g2, const float* __restrict__ b2,
    const float* __restrict__ Wf1, const float* __restrict__ bf1,
    const float* __restrict__ Wf2, const float* __restrict__ bf2,
    float* __restrict__ out)
{
    __shared__ float S[4][256];
    int tid = threadIdx.x, lane = tid & 63, w = tid >> 6;
    int row = blockIdx.x * 4 + w;
    S[w][lane] = hatt[(size_t)row * 64 + lane];
    __syncthreads();
    float h2 = h[(size_t)row * 64 + lane] + Ob[lane];
    #pragma unroll 8
    for (int k = 0; k < 64; ++k) h2 += S[w][k] * OW[k * 64 + lane];
    float m = wredsum(h2) * (1.f / 64.f);
    float t = h2 - m;
    float var = wredsum(t * t) * (1.f / 64.f);
    float y = t * rsqrtf(var + 1e-5f) * g2[lane] + b2[lane];
    S[w][64 + lane] = y;
    __syncthreads();
    float u1 = bf1[lane], u2 = bf1[64 + lane];
    #pragma unroll 8
    for (int k = 0; k < 64; ++k) {
        float yk = S[w][64 + k];
        u1 += yk * Wf1[k * 128 + lane];
        u2 += yk * Wf1[k * 128 + 64 + lane];
    }
    S[w][128 + lane] = fmaxf(u1, 0.f);
    S[w][192 + lane] = fmaxf(u2, 0.f);
    __syncthreads();
    float f = bf2[lane];
    #pragma unroll 8
    for (int c = 0; c < 128; ++c) f += S[w][128 + c] * Wf2[c * 64 + lane];
    out[(size_t)row * 64 + lane] = h2 + f;
}

extern "C" void kernel_launch(void* const* d_in, const int* in_sizes, int n_in,
                              void* d_out, int out_size, void* d_ws, size_t ws_size,
                              hipStream_t stream)
{
    const float* h   = (const float*)d_in[0];
    const float* p   = (const float*)d_in[1];
    const float* e   = (const float*)d_in[2];
    const float* kRW = (const float*)d_in[3];
    const float* mask= (const float*)d_in[4];
    const int*   adj = (const int*)d_in[5];
    const float* WQ  = (const float*)d_in[6];
    const float* WK  = (const float*)d_in[7];
    const float* WV  = (const float*)d_in[8];
    const float* WQ2 = (const float*)d_in[9];
    const float* WK2 = (const float*)d_in[10];
    const float* WE  = (const float*)d_in[11];
    const float* WE2 = (const float*)d_in[12];
    const float* OW  = (const float*)d_in[13];
    const float* Ob  = (const float*)d_in[14];
    const float* g1  = (const float*)d_in[15];
    const float* b1  = (const float*)d_in[16];
    const float* g2  = (const float*)d_in[17];
    const float* b2  = (const float*)d_in[18];
    const float* Wf1 = (const float*)d_in[19];
    const float* bf1 = (const float*)d_in[20];
    const float* Wf2 = (const float*)d_in[21];
    const float* bf2 = (const float*)d_in[22];
    float* out = (float*)d_out;

    float* ws = (float*)d_ws;
    float* Q1w = ws;
    float* K1w = ws + 131072;
    float* Q2w = ws + 262144;
    float* K2w = ws + 393216;
    float* Vw  = ws + 524288;
    float* hatt= ws + 655360;

    k1_ln_proj<<<128, 256, 0, stream>>>(h, p, WQ, WK, WV, WQ2, WK2, g1, b1,
                                        Q1w, K1w, Vw, Q2w, K2w);
    k2_attn<<<2048, 256, 0, stream>>>(e, adj, kRW, mask, WE, WE2,
                                      Q1w, K1w, Q2w, K2w, Vw, hatt);
    k3_out<<<512, 256, 0, stream>>>(hatt, h, OW, Ob, g2, b2, Wf1, bf1, Wf2, bf2, out);
}

// Round 4
// 479.422 us; speedup vs baseline: 1.0658x; 1.0658x over previous
//
#include <hip/hip_runtime.h>
#include <stdint.h>

// GraphiT GT layer, B=4, N=512, D=64, H=8, DH=8.
// K1: x = LN(h+p); Q1,K1s,V,Q2,K2s projections (K's pre-scaled by 8^-0.5)
// K2: per (b,i): barrier-free streaming attention; MFMA for (e@W_E)·Q per tile.
//     EvL is WAVE-PRIVATE -> no __syncthreads in the main loop; 1-deep prefetch.
// K3: h2 = h + hatt@O_W + O_b; out = h2 + FFN(LN2(h2))

typedef __attribute__((ext_vector_type(8))) short short8;
typedef __attribute__((ext_vector_type(4))) float f32x4;

__device__ __forceinline__ unsigned short f2bf(float f) {
    unsigned int u = __float_as_uint(f);
    u = (u + 0x7fffu + ((u >> 16) & 1u)) >> 16;   // RNE to bf16
    return (unsigned short)u;
}

__device__ __forceinline__ float wredsum(float v) {
    v += __shfl_xor(v, 1, 64);
    v += __shfl_xor(v, 2, 64);
    v += __shfl_xor(v, 4, 64);
    v += __shfl_xor(v, 8, 64);
    v += __shfl_xor(v, 16, 64);
    v += __shfl_xor(v, 32, 64);
    return v;
}

// ---------------- K1: LN(h+p) + 5 projections ----------------
// 256 blocks x 8 rows: 2 waves/SIMD across all CUs.
__global__ __launch_bounds__(256) void k1_ln_proj(
    const float* __restrict__ h, const float* __restrict__ p,
    const float* __restrict__ WQ, const float* __restrict__ WK,
    const float* __restrict__ WV, const float* __restrict__ WQ2,
    const float* __restrict__ WK2,
    const float* __restrict__ g1, const float* __restrict__ b1,
    float* __restrict__ Q1w, float* __restrict__ K1w,
    float* __restrict__ Vw, float* __restrict__ Q2w, float* __restrict__ K2w)
{
    __shared__ float xl[8][64];
    int tid = threadIdx.x, lane = tid & 63, w = tid >> 6;
    int row0 = blockIdx.x * 8;
    for (int rr = 0; rr < 2; ++rr) {
        int r = w * 2 + rr;
        int row = row0 + r;
        float v = h[row * 64 + lane] + p[row * 64 + lane];
        float m = wredsum(v) * (1.0f / 64.0f);
        float t = v - m;
        float var = wredsum(t * t) * (1.0f / 64.0f);
        xl[r][lane] = t * rsqrtf(var + 1e-5f) * g1[lane] + b1[lane];
    }
    __syncthreads();
    const float* Ws[5] = {WQ, WK, WV, WQ2, WK2};
    float* Os[5] = {Q1w, K1w, Vw, Q2w, K2w};
    const float scale = 0.35355339059327373f; // DH^-0.5
    for (int idx = tid; idx < 5 * 8 * 64; idx += 256) {
        int m = idx >> 9;
        int rem = idx & 511;
        int r = rem >> 6;
        int c = rem & 63;
        const float* W = Ws[m];
        float acc = 0.f;
        #pragma unroll 8
        for (int d = 0; d < 64; ++d) acc += xl[r][d] * W[d * 64 + c];
        if (m == 1 || m == 4) acc *= scale;
        Os[m][(row0 + r) * 64 + c] = acc;
    }
}

// ---------------- K2: main fused attention ----------------
// block = (b,i); 256 threads = 4 waves; each wave handles 8 tiles of 16 j's.
__global__ __launch_bounds__(256) void k2_attn(
    const float* __restrict__ e, const int* __restrict__ adj,
    const float* __restrict__ kRW, const float* __restrict__ mask,
    const float* __restrict__ WE, const float* __restrict__ WE2,
    const float* __restrict__ Q1w, const float* __restrict__ K1w,
    const float* __restrict__ Q2w, const float* __restrict__ K2w,
    const float* __restrict__ Vw, float* __restrict__ hatt)
{
    __shared__ __align__(16) float EvL[4][16][132];  // wave-private Ev tiles
    __shared__ float red[4][4][18];
    int tid = threadIdx.x, lane = tid & 63, w = tid >> 6;
    int lm = lane & 15, lg = lane >> 4;
    int blk = blockIdx.x;
    int b = blk >> 9;
    const float mi = mask[(size_t)blk];   // mask[b*512+i] == mask[blk]

    // B fragments: W_E (and W_E2) columns scaled by Q1 (Q2) of this row i.
    // mfma 16x16x32 bf16 B layout: lane holds B[k = 8*(lane/16)+e][col = lane%16]
    short8 bf[2][4][2];
    {
        const float* Q1r = Q1w + (size_t)blk * 64;
        const float* Q2r = Q2w + (size_t)blk * 64;
        #pragma unroll
        for (int mat = 0; mat < 2; ++mat) {
            const float* W = mat ? WE2 : WE;
            const float* Qr = mat ? Q2r : Q1r;
            #pragma unroll
            for (int t = 0; t < 4; ++t) {
                int c = t * 16 + lm;
                float qv = Qr[c];
                #pragma unroll
                for (int s = 0; s < 2; ++s) {
                    short8 v;
                    #pragma unroll
                    for (int ei = 0; ei < 8; ++ei)
                        v[ei] = (short)f2bf(W[(s * 32 + lg * 8 + ei) * 64 + c] * qv);
                    bf[mat][t][s] = v;
                }
            }
        }
    }

    float nr[16];
    #pragma unroll
    for (int q = 0; q < 16; ++q) nr[q] = 0.f;
    float den0 = 0.f, den1 = 0.f;

    const float* eblk = e + (size_t)blk * 32768;
    int jl = lane >> 2, pp = lane & 3;

    // ---- 1-deep prefetch state (iteration 0) ----
    float4 pf0, pf1, pf2, pf3;
    int pav; float pkk, pmj;
    {
        int jbase = w * 16;
        const float* erow = eblk + (size_t)(jbase + lm) * 64 + lg * 8;
        pf0 = *(const float4*)(erow);
        pf1 = *(const float4*)(erow + 4);
        pf2 = *(const float4*)(erow + 32);
        pf3 = *(const float4*)(erow + 36);
        int j = jbase + jl;
        size_t pair = (size_t)blk * 512 + j;
        pav = adj[pair];
        pkk = kRW[pair];
        pmj = mask[b * 512 + j];
    }

    #pragma unroll
    for (int it = 0; it < 8; ++it) {
        float4 f0 = pf0, f1 = pf1, f2v = pf2, f3 = pf3;
        int av = pav; float kk = pkk, mj = pmj;
        if (it < 7) {   // issue next-iteration loads early; latency hides under MFMA+phase2
            int jb2 = ((it + 1) * 4 + w) * 16;
            const float* erow = eblk + (size_t)(jb2 + lm) * 64 + lg * 8;
            pf0 = *(const float4*)(erow);
            pf1 = *(const float4*)(erow + 4);
            pf2 = *(const float4*)(erow + 32);
            pf3 = *(const float4*)(erow + 36);
            int j2 = jb2 + jl;
            size_t pair2 = (size_t)blk * 512 + j2;
            pav = adj[pair2];
            pkk = kRW[pair2];
            pmj = mask[b * 512 + j2];
        }
        int jbase = (it * 4 + w) * 16;

        // A fragments: lane holds e_tile[row = lane%16][k = 8*(lane/16)+e] per 32-wide K step
        short8 a0, a1;
        a0[0]=(short)f2bf(f0.x); a0[1]=(short)f2bf(f0.y); a0[2]=(short)f2bf(f0.z); a0[3]=(short)f2bf(f0.w);
        a0[4]=(short)f2bf(f1.x); a0[5]=(short)f2bf(f1.y); a0[6]=(short)f2bf(f1.z); a0[7]=(short)f2bf(f1.w);
        a1[0]=(short)f2bf(f2v.x); a1[1]=(short)f2bf(f2v.y); a1[2]=(short)f2bf(f2v.z); a1[3]=(short)f2bf(f2v.w);
        a1[4]=(short)f2bf(f3.x); a1[5]=(short)f2bf(f3.y); a1[6]=(short)f2bf(f3.z); a1[7]=(short)f2bf(f3.w);

        #pragma unroll
        for (int mat = 0; mat < 2; ++mat) {
            #pragma unroll
            for (int t = 0; t < 4; ++t) {
                f32x4 acc = {0.f, 0.f, 0.f, 0.f};
                acc = __builtin_amdgcn_mfma_f32_16x16x32_bf16(a0, bf[mat][t][0], acc, 0, 0, 0);
                acc = __builtin_amdgcn_mfma_f32_16x16x32_bf16(a1, bf[mat][t][1], acc, 0, 0, 0);
                // C/D layout (m89-verified): col = lane&15, row = (lane>>4)*4 + reg
                #pragma unroll
                for (int ei = 0; ei < 4; ++ei)
                    EvL[w][lg * 4 + ei][mat * 64 + t * 16 + lm] = acc[ei];
            }
        }
        // NO __syncthreads: EvL[w] is wave-private; same-wave LDS write->read is
        // ordered by the compiler's lgkmcnt waits.

        // phase 2: 4 lanes per j; lane pp owns flat hk in [pp*16, pp*16+16) == heads 2pp, 2pp+1
        int j = jbase + jl;
        float mj_i = mj * mi;
        size_t jrow = (size_t)(b * 512 + j) * 64 + pp * 16;
        const float* Ks = (av ? K1w : K2w) + jrow;
        const float* Vp = Vw + jrow;
        const float* Evp = &EvL[w][jl][(av ? 0 : 64) + pp * 16];

        float4 ev0 = *(const float4*)(Evp);
        float4 ev1 = *(const float4*)(Evp + 4);
        float4 ev2 = *(const float4*)(Evp + 8);
        float4 ev3 = *(const float4*)(Evp + 12);
        float4 ka = *(const float4*)(Ks);
        float4 kb = *(const float4*)(Ks + 4);
        float4 kc = *(const float4*)(Ks + 8);
        float4 kd = *(const float4*)(Ks + 12);
        float s0 = ev0.x*ka.x + ev0.y*ka.y + ev0.z*ka.z + ev0.w*ka.w
                 + ev1.x*kb.x + ev1.y*kb.y + ev1.z*kb.z + ev1.w*kb.w;
        float s1 = ev2.x*kc.x + ev2.y*kc.y + ev2.z*kc.z + ev2.w*kc.w
                 + ev3.x*kd.x + ev3.y*kd.y + ev3.z*kd.z + ev3.w*kd.w;
        float w0 = __expf(s0) * kk * mj_i;
        float w1 = __expf(s1) * kk * mj_i;

        float4 va = *(const float4*)(Vp);
        float4 vb = *(const float4*)(Vp + 4);
        float4 vc = *(const float4*)(Vp + 8);
        float4 vd = *(const float4*)(Vp + 12);
        nr[0] += w0 * va.x;  nr[1] += w0 * va.y;  nr[2] += w0 * va.z;  nr[3] += w0 * va.w;
        nr[4] += w0 * vb.x;  nr[5] += w0 * vb.y;  nr[6] += w0 * vb.z;  nr[7] += w0 * vb.w;
        nr[8] += w1 * vc.x;  nr[9] += w1 * vc.y;  nr[10] += w1 * vc.z; nr[11] += w1 * vc.w;
        nr[12] += w1 * vd.x; nr[13] += w1 * vd.y; nr[14] += w1 * vd.z; nr[15] += w1 * vd.w;
        den0 += w0; den1 += w1;
    }

    // reduce across the 16 j-owner lanes per pp within the wave
    #pragma unroll
    for (int q = 0; q < 16; ++q) {
        nr[q] += __shfl_xor(nr[q], 4, 64);
        nr[q] += __shfl_xor(nr[q], 8, 64);
        nr[q] += __shfl_xor(nr[q], 16, 64);
        nr[q] += __shfl_xor(nr[q], 32, 64);
    }
    den0 += __shfl_xor(den0, 4, 64); den0 += __shfl_xor(den0, 8, 64);
    den0 += __shfl_xor(den0, 16, 64); den0 += __shfl_xor(den0, 32, 64);
    den1 += __shfl_xor(den1, 4, 64); den1 += __shfl_xor(den1, 8, 64);
    den1 += __shfl_xor(den1, 16, 64); den1 += __shfl_xor(den1, 32, 64);

    if (jl == 0) {  // lanes 0..3 carry pp = 0..3
        #pragma unroll
        for (int q = 0; q < 16; ++q) red[w][pp][q] = nr[q];
        red[w][pp][16] = den0;
        red[w][pp][17] = den1;
    }
    __syncthreads();
    if (tid < 64) {
        int p2 = tid >> 4, q = tid & 15;
        float ns = red[0][p2][q] + red[1][p2][q] + red[2][p2][q] + red[3][p2][q];
        int di = 16 + (q >> 3);
        float ds = red[0][p2][di] + red[1][p2][di] + red[2][p2][di] + red[3][p2][di];
        hatt[(size_t)blk * 64 + p2 * 16 + q] = ns / fmaxf(ds, 1e-6f);
    }
}

// ---------------- K3: output projection + residual + LN2 + FFN ----------------
__global__ __launch_bounds__(256) void k3_out(
    const float* __restrict__ hatt, const float* __restrict__ h,
    const float* __restrict__ OW, const float* __restrict__ Ob,
    const float* __restrict__ g2, const float* __restrict__ b2,
    const float* __restrict__ Wf1, const float* __restrict__ bf1,
    const float* __restrict__ Wf2, const float* __restrict__ bf2,
    float* __restrict__ out)
{
    __shared__ float S[4][256];
    int tid = threadIdx.x, lane = tid & 63, w = tid >> 6;
    int row = blockIdx.x * 4 + w;
    S[w][lane] = hatt[(size_t)row * 64 + lane];
    __syncthreads();
    float h2 = h[(size_t)row * 64 + lane] + Ob[lane];
    #pragma unroll 8
    for (int k = 0; k < 64; ++k) h2 += S[w][k] * OW[k * 64 + lane];
    float m = wredsum(h2) * (1.f / 64.f);
    float t = h2 - m;
    float var = wredsum(t * t) * (1.f / 64.f);
    float y = t * rsqrtf(var + 1e-5f) * g2[lane] + b2[lane];
    S[w][64 + lane] = y;
    __syncthreads();
    float u1 = bf1[lane], u2 = bf1[64 + lane];
    #pragma unroll 8
    for (int k = 0; k < 64; ++k) {
        float yk = S[w][64 + k];
        u1 += yk * Wf1[k * 128 + lane];
        u2 += yk * Wf1[k * 128 + 64 + lane];
    }
    S[w][128 + lane] = fmaxf(u1, 0.f);
    S[w][192 + lane] = fmaxf(u2, 0.f);
    __syncthreads();
    float f = bf2[lane];
    #pragma unroll 8
    for (int c = 0; c < 128; ++c) f += S[w][128 + c] * Wf2[c * 64 + lane];
    out[(size_t)row * 64 + lane] = h2 + f;
}

extern "C" void kernel_launch(void* const* d_in, const int* in_sizes, int n_in,
                              void* d_out, int out_size, void* d_ws, size_t ws_size,
                              hipStream_t stream)
{
    const float* h   = (const float*)d_in[0];
    const float* p   = (const float*)d_in[1];
    const float* e   = (const float*)d_in[2];
    const float* kRW = (const float*)d_in[3];
    const float* mask= (const float*)d_in[4];
    const int*   adj = (const int*)d_in[5];
    const float* WQ  = (const float*)d_in[6];
    const float* WK  = (const float*)d_in[7];
    const float* WV  = (const float*)d_in[8];
    const float* WQ2 = (const float*)d_in[9];
    const float* WK2 = (const float*)d_in[10];
    const float* WE  = (const float*)d_in[11];
    const float* WE2 = (const float*)d_in[12];
    const float* OW  = (const float*)d_in[13];
    const float* Ob  = (const float*)d_in[14];
    const float* g1  = (const float*)d_in[15];
    const float* b1  = (const float*)d_in[16];
    const float* g2  = (const float*)d_in[17];
    const float* b2  = (const float*)d_in[18];
    const float* Wf1 = (const float*)d_in[19];
    const float* bf1 = (const float*)d_in[20];
    const float* Wf2 = (const float*)d_in[21];
    const float* bf2 = (const float*)d_in[22];
    float* out = (float*)d_out;

    float* ws = (float*)d_ws;
    float* Q1w = ws;
    float* K1w = ws + 131072;
    float* Q2w = ws + 262144;
    float* K2w = ws + 393216;
    float* Vw  = ws + 524288;
    float* hatt= ws + 655360;

    k1_ln_proj<<<256, 256, 0, stream>>>(h, p, WQ, WK, WV, WQ2, WK2, g1, b1,
                                        Q1w, K1w, Vw, Q2w, K2w);
    k2_attn<<<2048, 256, 0, stream>>>(e, adj, kRW, mask, WE, WE2,
                                      Q1w, K1w, Q2w, K2w, Vw, hatt);
    k3_out<<<512, 256, 0, stream>>>(hatt, h, OW, Ob, g2, b2, Wf1, bf1, Wf2, bf2, out);
}